// Round 11
// baseline (447.514 us; speedup 1.0000x reference)
//
#include <hip/hip_runtime.h>
#include <hip/hip_bf16.h>
#include <cmath>

#define B_ 2
#define L_ 1024
#define DM 1024
#define DI 2048
#define NS 16
#define RR 64
#define KC 4
#define NCH 32
#define CL (L_ / NCH)   // 32
#define NSPLIT 16       // dbl GEMM split-K factor

using frag8 = __attribute__((ext_vector_type(8))) short;   // 8 bf16 (4 VGPRs)
using facc4 = __attribute__((ext_vector_type(4))) float;   // MFMA C/D

__device__ __forceinline__ short f2b(float v) {
    __hip_bfloat16 h = __float2bfloat16(v);
    return *(short*)&h;
}

// powers pw[n] = q^(n+1), binary-tree (depth 4, 15 independent muls)
__device__ __forceinline__ void pow_tree(float q, float* pw) {
    float q2 = q * q, q4 = q2 * q2, q8 = q4 * q4;
    pw[0] = q;        pw[1] = q2;       pw[2] = q2 * q;   pw[3] = q4;
    pw[4] = q4 * q;   pw[5] = q4 * q2;  pw[6] = q4 * pw[2]; pw[7] = q8;
    pw[8] = q8 * q;   pw[9] = q8 * q2;  pw[10] = q8 * pw[2]; pw[11] = q8 * q4;
    pw[12] = q8 * pw[4]; pw[13] = q8 * pw[5]; pw[14] = q8 * pw[6]; pw[15] = q8 * q8;
}

// async global->LDS DMA, 16 B per lane. LDS dest is wave-uniform base + lane*16.
__device__ __forceinline__ void async_ld16(const void* g, void* l) {
    __builtin_amdgcn_global_load_lds(
        (const __attribute__((address_space(1))) unsigned int*)g,
        (__attribute__((address_space(3))) unsigned int*)l, 16, 0, 0);
}

// fp32 -> bf16 cast; optional per-batch flip along L (rows = b*Lseq + l)
__global__ void cvt_bf16(const float* __restrict__ x, short* __restrict__ y,
                         int rows, int cols, int Lseq, int flip) {
    int idx = blockIdx.x * blockDim.x + threadIdx.x;
    if (idx >= rows * cols) return;
    int r = idx / cols, c = idx % cols;
    int sr = r;
    if (flip) { int bb = r / Lseq, ll = r % Lseq; sr = bb * Lseq + (Lseq - 1 - ll); }
    y[(size_t)r * cols + c] = f2b(x[(size_t)sr * cols + c]);
}

// one launch converting all the small weights
__global__ void cvt_weights(const float* __restrict__ Wx, const float* __restrict__ Wxb,
                            const float* __restrict__ Wdt, const float* __restrict__ Wdtb,
                            const float* __restrict__ Wo,
                            short* __restrict__ oWx, short* __restrict__ oWxb,
                            short* __restrict__ oWdt, short* __restrict__ oWdtb,
                            short* __restrict__ oWo) {
    int i = blockIdx.x * blockDim.x + threadIdx.x;
    const int S0 = 96 * DI, S2 = DI * RR, S4 = DM * DI;
    if (i < S0) { oWx[i] = f2b(Wx[i]); return; } i -= S0;
    if (i < S0) { oWxb[i] = f2b(Wxb[i]); return; } i -= S0;
    if (i < S2) { oWdt[i] = f2b(Wdt[i]); return; } i -= S2;
    if (i < S2) { oWdtb[i] = f2b(Wdtb[i]); return; } i -= S2;
    if (i < S4) { oWo[i] = f2b(Wo[i]); }
}

// MFMA bf16 GEMM: C[M,N] = A[M,K] * W[N,K]^T, tile BM x 64, BK=32,
// double-buffered LDS: sync -> prefetch(next into other buf) -> compute(cur).
template <int BM>
__global__ __launch_bounds__(256) void gemm_mfma(
    const short* __restrict__ A, int lda,
    const short* __restrict__ W, int ldw, int wRowOff,
    float* __restrict__ C, int ldc, int K) {
    constexpr int MF = BM / 32;
    __shared__ __align__(16) short As[2][BM * 32];
    __shared__ __align__(16) short Ws[2][64 * 32];
    const int tid = threadIdx.x;
    const int lane = tid & 63, wv = tid >> 6;
    const int m0 = blockIdx.y * BM, n0 = blockIdx.x * 64;
    const int wm = (wv & 1) * (BM / 2), wn = (wv >> 1) * 32;
    const int q = lane >> 4, mr = lane & 15;
    const int srow = lane >> 2, skb = lane & 3;

    const short* Ag = A + (size_t)(m0 + wv * 16 + srow) * lda + skb * 8;
    const short* Wg = W + (size_t)(n0 + wRowOff + wv * 16 + srow) * ldw + skb * 8;

    facc4 acc[MF][2];
#pragma unroll
    for (int i = 0; i < MF; ++i)
#pragma unroll
        for (int j = 0; j < 2; ++j) acc[i][j] = (facc4){0.f, 0.f, 0.f, 0.f};

    async_ld16(Ag, &As[0][wv * 512]);
    if constexpr (BM == 128) async_ld16(Ag + (size_t)64 * lda, &As[0][wv * 512 + 2048]);
    async_ld16(Wg, &Ws[0][wv * 512]);

    const int nk = K / 32;
    for (int it = 0; it < nk; ++it) {
        const int buf = it & 1;
        __syncthreads();
        if (it + 1 < nk) {
            int k0 = (it + 1) * 32;
            async_ld16(Ag + k0, &As[buf ^ 1][wv * 512]);
            if constexpr (BM == 128)
                async_ld16(Ag + (size_t)64 * lda + k0, &As[buf ^ 1][wv * 512 + 2048]);
            async_ld16(Wg + k0, &Ws[buf ^ 1][wv * 512]);
        }
        frag8 af[MF], wf[2];
#pragma unroll
        for (int t = 0; t < MF; ++t)
            af[t] = *(const frag8*)&As[buf][((wm + t * 16 + mr) * 4 + q) * 8];
#pragma unroll
        for (int j = 0; j < 2; ++j)
            wf[j] = *(const frag8*)&Ws[buf][((wn + j * 16 + mr) * 4 + q) * 8];
#pragma unroll
        for (int i = 0; i < MF; ++i)
#pragma unroll
            for (int j = 0; j < 2; ++j)
                acc[i][j] = __builtin_amdgcn_mfma_f32_16x16x32_bf16(af[i], wf[j], acc[i][j], 0, 0, 0);
    }
#pragma unroll
    for (int i = 0; i < MF; ++i)
#pragma unroll
        for (int j = 0; j < 2; ++j) {
            int gn = n0 + wn + j * 16 + mr;
#pragma unroll
            for (int e = 0; e < 4; ++e) {
                int gm = m0 + wm + i * 16 + q * 4 + e;
                C[(size_t)gm * ldc + gn] = acc[i][j][e];
            }
        }
}

// dbl GEMM: part[z][M][96] = A[M, kchunk] * W[96, kchunk]^T (tile 128x96, split-K, dbuf)
__global__ __launch_bounds__(256) void gemm_mfma_dbl(
    const short* __restrict__ A, int lda,
    const short* __restrict__ W, int ldw,
    float* __restrict__ part, int Kchunk) {
    __shared__ __align__(16) short As[2][128 * 32];
    __shared__ __align__(16) short Ws[2][96 * 32];
    const int tid = threadIdx.x;
    const int lane = tid & 63, wv = tid >> 6;
    const int m0 = blockIdx.y * 128;
    const int kOff = blockIdx.z * Kchunk;
    const int wm = (wv & 1) * 64, wn = (wv >> 1) * 48;
    const int q = lane >> 4, mr = lane & 15;
    const int srow = lane >> 2, skb = lane & 3;

    const short* Ag = A + (size_t)(m0 + wv * 16 + srow) * lda + skb * 8 + kOff;
    const short* Wg = W + (size_t)(wv * 16 + srow) * ldw + skb * 8 + kOff;

    facc4 acc[4][3];
#pragma unroll
    for (int i = 0; i < 4; ++i)
#pragma unroll
        for (int j = 0; j < 3; ++j) acc[i][j] = (facc4){0.f, 0.f, 0.f, 0.f};

    async_ld16(Ag, &As[0][wv * 512]);
    async_ld16(Ag + (size_t)64 * lda, &As[0][wv * 512 + 2048]);
    async_ld16(Wg, &Ws[0][wv * 512]);
    if (wv < 2) async_ld16(Wg + (size_t)64 * ldw, &Ws[0][wv * 512 + 2048]);

    const int nk = Kchunk / 32;
    for (int it = 0; it < nk; ++it) {
        const int buf = it & 1;
        __syncthreads();
        if (it + 1 < nk) {
            int k0 = (it + 1) * 32;
            async_ld16(Ag + k0, &As[buf ^ 1][wv * 512]);
            async_ld16(Ag + (size_t)64 * lda + k0, &As[buf ^ 1][wv * 512 + 2048]);
            async_ld16(Wg + k0, &Ws[buf ^ 1][wv * 512]);
            if (wv < 2) async_ld16(Wg + (size_t)64 * ldw + k0, &Ws[buf ^ 1][wv * 512 + 2048]);
        }
        frag8 af[4], wf[3];
#pragma unroll
        for (int t = 0; t < 4; ++t)
            af[t] = *(const frag8*)&As[buf][((wm + t * 16 + mr) * 4 + q) * 8];
#pragma unroll
        for (int j = 0; j < 3; ++j)
            wf[j] = *(const frag8*)&Ws[buf][((wn + j * 16 + mr) * 4 + q) * 8];
#pragma unroll
        for (int i = 0; i < 4; ++i)
#pragma unroll
            for (int j = 0; j < 3; ++j)
                acc[i][j] = __builtin_amdgcn_mfma_f32_16x16x32_bf16(af[i], wf[j], acc[i][j], 0, 0, 0);
    }
    float* Cz = part + (size_t)blockIdx.z * (B_ * L_) * 96;
#pragma unroll
    for (int i = 0; i < 4; ++i)
#pragma unroll
        for (int j = 0; j < 3; ++j) {
            int gn = wn + j * 16 + mr;
#pragma unroll
            for (int e = 0; e < 4; ++e) {
                int gm = m0 + wm + i * 16 + q * 4 + e;
                Cz[(size_t)gm * 96 + gn] = acc[i][j][e];
            }
        }
}

// sum split-K partials -> dbl fp32; cols 0..63 also -> bf16 dt operand
__global__ void reduce_dbl(const float* __restrict__ part, float* __restrict__ dbl,
                           short* __restrict__ dtbf) {
    int idx = blockIdx.x * blockDim.x + threadIdx.x;
    const int T = B_ * L_ * 96;
    if (idx >= T) return;
    float s = 0.f;
#pragma unroll
    for (int z = 0; z < NSPLIT; ++z) s += part[(size_t)z * T + idx];
    dbl[idx] = s;
    int row = idx / 96, col = idx % 96;
    if (col < RR) dtbf[(size_t)row * RR + col] = f2b(s);
}

// depthwise causal conv (K=4) + bias + SiLU; fp32 + bf16 outputs
__global__ void conv_silu_dual(const float* __restrict__ x,
                               const float* __restrict__ w,
                               const float* __restrict__ bias,
                               float* __restrict__ y, short* __restrict__ ybf,
                               int total) {
    int idx = blockIdx.x * blockDim.x + threadIdx.x;
    if (idx >= total) return;
    int d = idx % DI;
    int l = (idx / DI) % L_;
    float acc = bias[d];
#pragma unroll
    for (int k = 0; k < KC; ++k) {
        int ls = l + k - (KC - 1);
        if (ls >= 0) acc += x[idx + (size_t)(ls - l) * DI] * w[d * KC + k];
    }
    float s = 1.f / (1.f + __expf(-acc));
    float v = acc * s;
    y[idx] = v;
    ybf[idx] = f2b(v);
}

__device__ __forceinline__ float softplus2(float raw, float bd2) {
    float x = raw + bd2;
    return (x > 20.f) ? x : log1pf(__expf(x));
}

// Pass A (fused local scan): reads u (B-buf) + raw dt (D-buf); writes
//   y_local (+u*D) over u, cumulative-delta over dt, P/S chunk states.
// Exploits A[n] = (n+1)*A[0] (runtime-verified): dA_n = q^(n+1) via pow-tree;
// C-dot uses 4 partial accumulators to break the fp32 dependence chain.
__global__ void scan_chunk(float* u, float* dtm,
                           const float* __restrict__ bdt,
                           const float* __restrict__ dbl,
                           const float* __restrict__ A_log,
                           const float* __restrict__ Dv,
                           float* __restrict__ Pbuf, float* __restrict__ Sbuf) {
    __shared__ float BCs[CL][32];
    const int tid = threadIdx.x;
    const int d = blockIdx.x * 256 + tid;
    const int bb = blockIdx.y, c = blockIdx.z;
    const int l0 = c * CL;
    {
        int e = tid * 4;   // CL*32 = 1024 floats
        int row = e >> 5, cc = e & 31;
        *(float4*)&BCs[row][cc] =
            *(const float4*)(dbl + ((size_t)(bb * L_ + l0 + row) * 96 + 64 + cc));
    }
    float Av[NS], S[NS];
#pragma unroll
    for (int n = 0; n < NS; ++n) { Av[n] = -__expf(A_log[d * NS + n]); S[n] = 0.f; }
    bool structured = true;
#pragma unroll
    for (int n = 1; n < NS; ++n)
        structured = structured &&
            (fabsf(Av[n] - (n + 1) * Av[0]) <= 1e-4f * (n + 1) * fabsf(Av[0]));
    const float bd2 = 2.f * bdt[d];
    const float Dd = Dv[d];
    float cd = 0.f;
    __syncthreads();
    float* up = u + ((size_t)bb * L_ + l0) * DI + d;
    float* dp = dtm + ((size_t)bb * L_ + l0) * DI + d;
    if (structured) {
        const float Av0 = Av[0];
        for (int l = 0; l < CL; ++l) {
            float del = softplus2(dp[(size_t)l * DI], bd2);
            cd += del;
            float ul = up[(size_t)l * DI];
            float du = del * ul;
            float pw[NS];
            pow_tree(__expf(del * Av0), pw);
            const float* Brow = &BCs[l][0];
            float pa[4] = {0.f, 0.f, 0.f, 0.f};
#pragma unroll
            for (int j = 0; j < 4; ++j)
#pragma unroll
                for (int k = 0; k < 4; ++k) {
                    int n = j * 4 + k;
                    S[n] = fmaf(pw[n], S[n], du * Brow[n]);
                    pa[j] = fmaf(S[n], Brow[16 + n], pa[j]);
                }
            float acc = (pa[0] + pa[1]) + (pa[2] + pa[3]);
            dp[(size_t)l * DI] = cd;
            up[(size_t)l * DI] = acc + ul * Dd;
        }
    } else {
        for (int l = 0; l < CL; ++l) {
            float del = softplus2(dp[(size_t)l * DI], bd2);
            cd += del;
            float ul = up[(size_t)l * DI];
            float du = del * ul;
            const float* Brow = &BCs[l][0];
            float pa[4] = {0.f, 0.f, 0.f, 0.f};
#pragma unroll
            for (int j = 0; j < 4; ++j)
#pragma unroll
                for (int k = 0; k < 4; ++k) {
                    int n = j * 4 + k;
                    float dA = __expf(del * Av[n]);
                    S[n] = fmaf(dA, S[n], du * Brow[n]);
                    pa[j] = fmaf(S[n], Brow[16 + n], pa[j]);
                }
            float acc = (pa[0] + pa[1]) + (pa[2] + pa[3]);
            dp[(size_t)l * DI] = cd;
            up[(size_t)l * DI] = acc + ul * Dd;
        }
    }
    size_t pb = ((size_t)(bb * NCH + c) * NS) * DI + d;
    if (structured) {
        float pw[NS];
        pow_tree(__expf(cd * Av[0]), pw);
#pragma unroll
        for (int n = 0; n < NS; ++n) {
            Pbuf[pb + (size_t)n * DI] = pw[n];
            Sbuf[pb + (size_t)n * DI] = S[n];
        }
    } else {
#pragma unroll
        for (int n = 0; n < NS; ++n) {
            Pbuf[pb + (size_t)n * DI] = __expf(cd * Av[n]);
            Sbuf[pb + (size_t)n * DI] = S[n];
        }
    }
}

// Pass B: one thread per (b,n,d); sequential over chunks. Pbuf[c] <- h_start[c].
__global__ void scan_combine(float* __restrict__ Pbuf, const float* __restrict__ Sbuf) {
    int g = blockIdx.x * blockDim.x + threadIdx.x;   // B_*NS*DI threads
    int d = g % DI;
    int rest = g / DI;
    int n = rest % NS, bb = rest / NS;
    float h = 0.f;
    for (int c = 0; c < NCH; ++c) {
        size_t o = ((size_t)(bb * NCH + c) * NS + n) * DI + d;
        float P = Pbuf[o], S = Sbuf[o];
        Pbuf[o] = h;
        h = P * h + S;
    }
}

// Pass C (correction, no recurrence): y[l] += sum_n C[l,n]*q^(n+1)*hs[n],
// q = exp(Av0*cd_l); pow-tree + 4 partial accumulators. Chunk 0 skipped.
__global__ void scan_apply(float* y, const float* __restrict__ cdm,
                           const float* __restrict__ dbl,
                           const float* __restrict__ A_log,
                           const float* __restrict__ Hbuf) {
    __shared__ float Cs[CL][16];
    const int tid = threadIdx.x;
    const int d = blockIdx.x * 256 + tid;
    const int bb = blockIdx.y, c = blockIdx.z + 1;
    const int l0 = c * CL;
    {
        int e = tid * 2;   // CL*16 = 512 floats
        int row = e >> 4, cc = e & 15;
        *(float2*)&Cs[row][cc] =
            *(const float2*)(dbl + ((size_t)(bb * L_ + l0 + row) * 96 + 80 + cc));
    }
    float Av[NS], chs[NS];
#pragma unroll
    for (int n = 0; n < NS; ++n) Av[n] = -__expf(A_log[d * NS + n]);
    bool structured = true;
#pragma unroll
    for (int n = 1; n < NS; ++n)
        structured = structured &&
            (fabsf(Av[n] - (n + 1) * Av[0]) <= 1e-4f * (n + 1) * fabsf(Av[0]));
    size_t pb = ((size_t)(bb * NCH + c) * NS) * DI + d;
#pragma unroll
    for (int n = 0; n < NS; ++n) chs[n] = Hbuf[pb + (size_t)n * DI];
    __syncthreads();
    const float* cp = cdm + ((size_t)bb * L_ + l0) * DI + d;
    float* yp = y + ((size_t)bb * L_ + l0) * DI + d;
    if (structured) {
        const float Av0 = Av[0];
        for (int l = 0; l < CL; ++l) {
            float cd = cp[(size_t)l * DI];
            float pw[NS];
            pow_tree(__expf(cd * Av0), pw);
            const float* Crow = &Cs[l][0];
            float pa[4] = {0.f, 0.f, 0.f, 0.f};
#pragma unroll
            for (int j = 0; j < 4; ++j)
#pragma unroll
                for (int k = 0; k < 4; ++k) {
                    int n = j * 4 + k;
                    pa[j] = fmaf(pw[n], Crow[n] * chs[n], pa[j]);
                }
            yp[(size_t)l * DI] += (pa[0] + pa[1]) + (pa[2] + pa[3]);
        }
    } else {
        for (int l = 0; l < CL; ++l) {
            float cd = cp[(size_t)l * DI];
            const float* Crow = &Cs[l][0];
            float pa[4] = {0.f, 0.f, 0.f, 0.f};
#pragma unroll
            for (int j = 0; j < 4; ++j)
#pragma unroll
                for (int k = 0; k < 4; ++k) {
                    int n = j * 4 + k;
                    pa[j] = fmaf(__expf(cd * Av[n]), Crow[n] * chs[n], pa[j]);
                }
            yp[(size_t)l * DI] += (pa[0] + pa[1]) + (pa[2] + pa[3]);
        }
    }
}

// g = (y_f + flip(y_b)) * silu(z); rmsnorm; emit bf16 for the final MFMA GEMM.
__global__ void combine_rms(const float* __restrict__ yf, const float* __restrict__ yb,
                            const float* __restrict__ z,
                            const float* __restrict__ nw,
                            short* __restrict__ g) {
    int row = blockIdx.x;
    int bb = row / L_, l = row % L_;
    int tid = threadIdx.x;
    size_t base = (size_t)row * DI;
    size_t baseb = ((size_t)bb * L_ + (L_ - 1 - l)) * DI;
    float gv[8];
    float ss = 0.f;
#pragma unroll
    for (int j = 0; j < 8; ++j) {
        int d = tid + j * 256;
        float yy = yf[base + d] + yb[baseb + d];
        float zz = z[base + d];
        float s = zz / (1.f + __expf(-zz));
        float gg = yy * s;
        gv[j] = gg;
        ss += gg * gg;
    }
#pragma unroll
    for (int off = 32; off > 0; off >>= 1) ss += __shfl_down(ss, off, 64);
    __shared__ float red[4];
    if ((tid & 63) == 0) red[tid >> 6] = ss;
    __syncthreads();
    float tot = red[0] + red[1] + red[2] + red[3];
    float rms = rsqrtf(tot / (float)DI + 1e-5f);
#pragma unroll
    for (int j = 0; j < 8; ++j) {
        int d = tid + j * 256;
        g[base + d] = f2b(gv[j] * rms * nw[d]);
    }
}

extern "C" void kernel_launch(void* const* d_in, const int* in_sizes, int n_in,
                              void* d_out, int out_size, void* d_ws, size_t ws_size,
                              hipStream_t stream) {
    const float* a      = (const float*)d_in[0];
    const float* b      = (const float*)d_in[1];
    const float* Wi     = (const float*)d_in[2];
    const float* conv_w = (const float*)d_in[3];
    const float* conv_b = (const float*)d_in[4];
    const float* Wx     = (const float*)d_in[5];
    const float* Wdt    = (const float*)d_in[6];
    const float* bdt    = (const float*)d_in[7];
    const float* A_log  = (const float*)d_in[8];
    const float* Dvec   = (const float*)d_in[9];
    const float* conv_w_b = (const float*)d_in[10];
    const float* conv_b_b = (const float*)d_in[11];
    const float* Wx_b   = (const float*)d_in[12];
    const float* Wdt_b  = (const float*)d_in[13];
    const float* bdt_b  = (const float*)d_in[14];
    const float* A_log_b = (const float*)d_in[15];
    const float* Dvec_b = (const float*)d_in[16];
    const float* Wo     = (const float*)d_in[17];
    const float* nw     = (const float*)d_in[18];
    float* out = (float*)d_out;

    const int M = B_ * L_;              // 2048
    const size_t BLD = (size_t)M * DI;  // 4194304
    const size_t NDBL = (size_t)M * 96; // 196608
    float* f = (float*)d_ws;
    float* B1   = f;                    // x_f -> cd_f | x_b -> cd_b -> z
    float* B2   = B1 + BLD;             // u_f -> y_f (final)
    float* B3   = B2 + BLD;             // u_b -> y_b (final)
    float* dblf = B3 + BLD;
    float* dblb = dblf + NDBL;
    float* part = dblb + NDBL;                       // NSPLIT*NDBL
    float* Pbuf = part + (size_t)NSPLIT * NDBL;
    float* Sbuf = Pbuf + (size_t)NCH * B_ * NS * DI;
    short* abf   = (short*)(Sbuf + (size_t)NCH * B_ * NS * DI);
    short* bbf   = abf + (size_t)M * DM;             // also gbf later
    short* Wibf  = bbf + (size_t)M * DM;
    short* cbf   = Wibf + (size_t)2 * DI * DM;
    short* Wxbf  = cbf + BLD;
    short* Wxbbf = Wxbf + (size_t)96 * DI;
    short* Wdtbf = Wxbbf + (size_t)96 * DI;
    short* Wdtbbf= Wdtbf + (size_t)DI * RR;
    short* dtbf  = Wdtbbf + (size_t)DI * RR;
    short* Wobf  = dtbf + (size_t)M * RR;
    short* gbf   = bbf;

    dim3 blk(256);
    const int totBLD = M * DI;
    dim3 chunkGrid(DI / 256, B_, NCH);
    dim3 applyGrid(DI / 256, B_, NCH - 1);
    const int nWeights = 2 * 96 * DI + 2 * DI * RR + DM * DI;

    // ---- casts ----
    cvt_bf16<<<dim3(M * DM / 256), blk, 0, stream>>>(a, abf, M, DM, L_, 0);
    cvt_bf16<<<dim3(M * DM / 256), blk, 0, stream>>>(b, bbf, M, DM, L_, 1);
    cvt_bf16<<<dim3(2 * DI * DM / 256), blk, 0, stream>>>(Wi, Wibf, 2 * DI, DM, L_, 0);
    cvt_weights<<<dim3((nWeights + 255) / 256), blk, 0, stream>>>(
        Wx, Wx_b, Wdt, Wdt_b, Wo, Wxbf, Wxbbf, Wdtbf, Wdtbbf, Wobf);

    // ---- forward branch ----
    gemm_mfma<128><<<dim3(DI / 64, M / 128), blk, 0, stream>>>(abf, DM, Wibf, DM, 0, B1, DI, DM);
    conv_silu_dual<<<dim3(totBLD / 256), blk, 0, stream>>>(B1, conv_w, conv_b, B2, cbf, totBLD);
    gemm_mfma_dbl<<<dim3(1, M / 128, NSPLIT), blk, 0, stream>>>(cbf, DI, Wxbf, DI, part, DI / NSPLIT);
    reduce_dbl<<<dim3((int)(NDBL / 256)), blk, 0, stream>>>(part, dblf, dtbf);
    gemm_mfma<64><<<dim3(DI / 64, M / 64), blk, 0, stream>>>(dtbf, RR, Wdtbf, RR, 0, B1, DI, RR);
    scan_chunk<<<chunkGrid, blk, 0, stream>>>(B2, B1, bdt, dblf, A_log, Dvec, Pbuf, Sbuf);
    scan_combine<<<dim3(B_ * NS * DI / 256), blk, 0, stream>>>(Pbuf, Sbuf);
    scan_apply<<<applyGrid, blk, 0, stream>>>(B2, B1, dblf, A_log, Pbuf);

    // ---- backward branch ----
    gemm_mfma<128><<<dim3(DI / 64, M / 128), blk, 0, stream>>>(bbf, DM, Wibf, DM, 0, B1, DI, DM);
    conv_silu_dual<<<dim3(totBLD / 256), blk, 0, stream>>>(B1, conv_w_b, conv_b_b, B3, cbf, totBLD);
    gemm_mfma_dbl<<<dim3(1, M / 128, NSPLIT), blk, 0, stream>>>(cbf, DI, Wxbbf, DI, part, DI / NSPLIT);
    reduce_dbl<<<dim3((int)(NDBL / 256)), blk, 0, stream>>>(part, dblb, dtbf);
    gemm_mfma<64><<<dim3(DI / 64, M / 64), blk, 0, stream>>>(dtbf, RR, Wdtbbf, RR, 0, B1, DI, RR);
    scan_chunk<<<chunkGrid, blk, 0, stream>>>(B3, B1, bdt_b, dblb, A_log_b, Dvec_b, Pbuf, Sbuf);
    scan_combine<<<dim3(B_ * NS * DI / 256), blk, 0, stream>>>(Pbuf, Sbuf);
    scan_apply<<<applyGrid, blk, 0, stream>>>(B3, B1, dblb, A_log_b, Pbuf);

    // ---- combine ----
    // z = a @ Wi[DI:2*DI].T -> B1 (cd_b dead)
    gemm_mfma<128><<<dim3(DI / 64, M / 128), blk, 0, stream>>>(abf, DM, Wibf, DM, DI, B1, DI, DM);
    combine_rms<<<dim3(M), blk, 0, stream>>>(B2, B3, B1, nw, gbf);
    gemm_mfma<64><<<dim3(DM / 64, M / 64), blk, 0, stream>>>(gbf, DI, Wobf, DI, 0, out, DM, DI);
}

// Round 12
// 412.799 us; speedup vs baseline: 1.0841x; 1.0841x over previous
//
#include <hip/hip_runtime.h>
#include <hip/hip_bf16.h>
#include <cmath>

#define B_ 2
#define L_ 1024
#define DM 1024
#define DI 2048
#define NS 16
#define RR 64
#define KC 4
#define NCH 64
#define CL (L_ / NCH)   // 16
#define NSPLIT 16       // dbl GEMM split-K factor

using frag8 = __attribute__((ext_vector_type(8))) short;   // 8 bf16 (4 VGPRs)
using facc4 = __attribute__((ext_vector_type(4))) float;   // MFMA C/D

__device__ __forceinline__ short f2b(float v) {
    __hip_bfloat16 h = __float2bfloat16(v);
    return *(short*)&h;
}

// powers pw[n] = q^(n+1), binary-tree (depth 4, 15 independent muls)
__device__ __forceinline__ void pow_tree(float q, float* pw) {
    float q2 = q * q, q4 = q2 * q2, q8 = q4 * q4;
    pw[0] = q;        pw[1] = q2;       pw[2] = q2 * q;   pw[3] = q4;
    pw[4] = q4 * q;   pw[5] = q4 * q2;  pw[6] = q4 * pw[2]; pw[7] = q8;
    pw[8] = q8 * q;   pw[9] = q8 * q2;  pw[10] = q8 * pw[2]; pw[11] = q8 * q4;
    pw[12] = q8 * pw[4]; pw[13] = q8 * pw[5]; pw[14] = q8 * pw[6]; pw[15] = q8 * q8;
}

// async global->LDS DMA, 16 B per lane. LDS dest is wave-uniform base + lane*16.
__device__ __forceinline__ void async_ld16(const void* g, void* l) {
    __builtin_amdgcn_global_load_lds(
        (const __attribute__((address_space(1))) unsigned int*)g,
        (__attribute__((address_space(3))) unsigned int*)l, 16, 0, 0);
}

// fp32 -> bf16 cast; optional per-batch flip along L (rows = b*Lseq + l)
__global__ void cvt_bf16(const float* __restrict__ x, short* __restrict__ y,
                         int rows, int cols, int Lseq, int flip) {
    int idx = blockIdx.x * blockDim.x + threadIdx.x;
    if (idx >= rows * cols) return;
    int r = idx / cols, c = idx % cols;
    int sr = r;
    if (flip) { int bb = r / Lseq, ll = r % Lseq; sr = bb * Lseq + (Lseq - 1 - ll); }
    y[(size_t)r * cols + c] = f2b(x[(size_t)sr * cols + c]);
}

// one launch converting all the small weights
__global__ void cvt_weights(const float* __restrict__ Wx, const float* __restrict__ Wxb,
                            const float* __restrict__ Wdt, const float* __restrict__ Wdtb,
                            const float* __restrict__ Wo,
                            short* __restrict__ oWx, short* __restrict__ oWxb,
                            short* __restrict__ oWdt, short* __restrict__ oWdtb,
                            short* __restrict__ oWo) {
    int i = blockIdx.x * blockDim.x + threadIdx.x;
    const int S0 = 96 * DI, S2 = DI * RR, S4 = DM * DI;
    if (i < S0) { oWx[i] = f2b(Wx[i]); return; } i -= S0;
    if (i < S0) { oWxb[i] = f2b(Wxb[i]); return; } i -= S0;
    if (i < S2) { oWdt[i] = f2b(Wdt[i]); return; } i -= S2;
    if (i < S2) { oWdtb[i] = f2b(Wdtb[i]); return; } i -= S2;
    if (i < S4) { oWo[i] = f2b(Wo[i]); }
}

// MFMA bf16 GEMM: C[M,N] = A[M,K] * W[N,K]^T, tile BM x 64, BK=32,
// double-buffered LDS: sync -> prefetch(next into other buf) -> compute(cur).
template <int BM>
__global__ __launch_bounds__(256) void gemm_mfma(
    const short* __restrict__ A, int lda,
    const short* __restrict__ W, int ldw, int wRowOff,
    float* __restrict__ C, int ldc, int K) {
    constexpr int MF = BM / 32;
    __shared__ __align__(16) short As[2][BM * 32];
    __shared__ __align__(16) short Ws[2][64 * 32];
    const int tid = threadIdx.x;
    const int lane = tid & 63, wv = tid >> 6;
    const int m0 = blockIdx.y * BM, n0 = blockIdx.x * 64;
    const int wm = (wv & 1) * (BM / 2), wn = (wv >> 1) * 32;
    const int q = lane >> 4, mr = lane & 15;
    const int srow = lane >> 2, skb = lane & 3;

    const short* Ag = A + (size_t)(m0 + wv * 16 + srow) * lda + skb * 8;
    const short* Wg = W + (size_t)(n0 + wRowOff + wv * 16 + srow) * ldw + skb * 8;

    facc4 acc[MF][2];
#pragma unroll
    for (int i = 0; i < MF; ++i)
#pragma unroll
        for (int j = 0; j < 2; ++j) acc[i][j] = (facc4){0.f, 0.f, 0.f, 0.f};

    async_ld16(Ag, &As[0][wv * 512]);
    if constexpr (BM == 128) async_ld16(Ag + (size_t)64 * lda, &As[0][wv * 512 + 2048]);
    async_ld16(Wg, &Ws[0][wv * 512]);

    const int nk = K / 32;
    for (int it = 0; it < nk; ++it) {
        const int buf = it & 1;
        __syncthreads();
        if (it + 1 < nk) {
            int k0 = (it + 1) * 32;
            async_ld16(Ag + k0, &As[buf ^ 1][wv * 512]);
            if constexpr (BM == 128)
                async_ld16(Ag + (size_t)64 * lda + k0, &As[buf ^ 1][wv * 512 + 2048]);
            async_ld16(Wg + k0, &Ws[buf ^ 1][wv * 512]);
        }
        frag8 af[MF], wf[2];
#pragma unroll
        for (int t = 0; t < MF; ++t)
            af[t] = *(const frag8*)&As[buf][((wm + t * 16 + mr) * 4 + q) * 8];
#pragma unroll
        for (int j = 0; j < 2; ++j)
            wf[j] = *(const frag8*)&Ws[buf][((wn + j * 16 + mr) * 4 + q) * 8];
#pragma unroll
        for (int i = 0; i < MF; ++i)
#pragma unroll
            for (int j = 0; j < 2; ++j)
                acc[i][j] = __builtin_amdgcn_mfma_f32_16x16x32_bf16(af[i], wf[j], acc[i][j], 0, 0, 0);
    }
#pragma unroll
    for (int i = 0; i < MF; ++i)
#pragma unroll
        for (int j = 0; j < 2; ++j) {
            int gn = n0 + wn + j * 16 + mr;
#pragma unroll
            for (int e = 0; e < 4; ++e) {
                int gm = m0 + wm + i * 16 + q * 4 + e;
                C[(size_t)gm * ldc + gn] = acc[i][j][e];
            }
        }
}

// dbl GEMM: part[z][M][96] = A[M, kchunk] * W[96, kchunk]^T (tile 128x96, split-K, dbuf)
__global__ __launch_bounds__(256) void gemm_mfma_dbl(
    const short* __restrict__ A, int lda,
    const short* __restrict__ W, int ldw,
    float* __restrict__ part, int Kchunk) {
    __shared__ __align__(16) short As[2][128 * 32];
    __shared__ __align__(16) short Ws[2][96 * 32];
    const int tid = threadIdx.x;
    const int lane = tid & 63, wv = tid >> 6;
    const int m0 = blockIdx.y * 128;
    const int kOff = blockIdx.z * Kchunk;
    const int wm = (wv & 1) * 64, wn = (wv >> 1) * 48;
    const int q = lane >> 4, mr = lane & 15;
    const int srow = lane >> 2, skb = lane & 3;

    const short* Ag = A + (size_t)(m0 + wv * 16 + srow) * lda + skb * 8 + kOff;
    const short* Wg = W + (size_t)(wv * 16 + srow) * ldw + skb * 8 + kOff;

    facc4 acc[4][3];
#pragma unroll
    for (int i = 0; i < 4; ++i)
#pragma unroll
        for (int j = 0; j < 3; ++j) acc[i][j] = (facc4){0.f, 0.f, 0.f, 0.f};

    async_ld16(Ag, &As[0][wv * 512]);
    async_ld16(Ag + (size_t)64 * lda, &As[0][wv * 512 + 2048]);
    async_ld16(Wg, &Ws[0][wv * 512]);
    if (wv < 2) async_ld16(Wg + (size_t)64 * ldw, &Ws[0][wv * 512 + 2048]);

    const int nk = Kchunk / 32;
    for (int it = 0; it < nk; ++it) {
        const int buf = it & 1;
        __syncthreads();
        if (it + 1 < nk) {
            int k0 = (it + 1) * 32;
            async_ld16(Ag + k0, &As[buf ^ 1][wv * 512]);
            async_ld16(Ag + (size_t)64 * lda + k0, &As[buf ^ 1][wv * 512 + 2048]);
            async_ld16(Wg + k0, &Ws[buf ^ 1][wv * 512]);
            if (wv < 2) async_ld16(Wg + (size_t)64 * ldw + k0, &Ws[buf ^ 1][wv * 512 + 2048]);
        }
        frag8 af[4], wf[3];
#pragma unroll
        for (int t = 0; t < 4; ++t)
            af[t] = *(const frag8*)&As[buf][((wm + t * 16 + mr) * 4 + q) * 8];
#pragma unroll
        for (int j = 0; j < 3; ++j)
            wf[j] = *(const frag8*)&Ws[buf][((wn + j * 16 + mr) * 4 + q) * 8];
#pragma unroll
        for (int i = 0; i < 4; ++i)
#pragma unroll
            for (int j = 0; j < 3; ++j)
                acc[i][j] = __builtin_amdgcn_mfma_f32_16x16x32_bf16(af[i], wf[j], acc[i][j], 0, 0, 0);
    }
    float* Cz = part + (size_t)blockIdx.z * (B_ * L_) * 96;
#pragma unroll
    for (int i = 0; i < 4; ++i)
#pragma unroll
        for (int j = 0; j < 3; ++j) {
            int gn = wn + j * 16 + mr;
#pragma unroll
            for (int e = 0; e < 4; ++e) {
                int gm = m0 + wm + i * 16 + q * 4 + e;
                Cz[(size_t)gm * 96 + gn] = acc[i][j][e];
            }
        }
}

// sum split-K partials -> dbl fp32; cols 0..63 also -> bf16 dt operand
__global__ void reduce_dbl(const float* __restrict__ part, float* __restrict__ dbl,
                           short* __restrict__ dtbf) {
    int idx = blockIdx.x * blockDim.x + threadIdx.x;
    const int T = B_ * L_ * 96;
    if (idx >= T) return;
    float s = 0.f;
#pragma unroll
    for (int z = 0; z < NSPLIT; ++z) s += part[(size_t)z * T + idx];
    dbl[idx] = s;
    int row = idx / 96, col = idx % 96;
    if (col < RR) dtbf[(size_t)row * RR + col] = f2b(s);
}

// depthwise causal conv (K=4) + bias + SiLU; fp32 + bf16 outputs
__global__ void conv_silu_dual(const float* __restrict__ x,
                               const float* __restrict__ w,
                               const float* __restrict__ bias,
                               float* __restrict__ y, short* __restrict__ ybf,
                               int total) {
    int idx = blockIdx.x * blockDim.x + threadIdx.x;
    if (idx >= total) return;
    int d = idx % DI;
    int l = (idx / DI) % L_;
    float acc = bias[d];
#pragma unroll
    for (int k = 0; k < KC; ++k) {
        int ls = l + k - (KC - 1);
        if (ls >= 0) acc += x[idx + (size_t)(ls - l) * DI] * w[d * KC + k];
    }
    float s = 1.f / (1.f + __expf(-acc));
    float v = acc * s;
    y[idx] = v;
    ybf[idx] = f2b(v);
}

__device__ __forceinline__ float softplus2(float raw, float bd2) {
    float x = raw + bd2;
    return (x > 20.f) ? x : log1pf(__expf(x));
}

// Pass A (fused local scan): reads u (B-buf) + raw dt (D-buf); writes
//   y_local (+u*D) over u, cumulative-delta over dt, P/S chunk states.
// Software-pipelined: next iteration's u/dt loads issue before this
// iteration's compute (u/dtm are distinct buffers -> __restrict__ legal).
__global__ void scan_chunk(float* __restrict__ u, float* __restrict__ dtm,
                           const float* __restrict__ bdt,
                           const float* __restrict__ dbl,
                           const float* __restrict__ A_log,
                           const float* __restrict__ Dv,
                           float* __restrict__ Pbuf, float* __restrict__ Sbuf) {
    __shared__ float BCs[CL][32];
    const int tid = threadIdx.x;
    const int d = blockIdx.x * 256 + tid;
    const int bb = blockIdx.y, c = blockIdx.z;
    const int l0 = c * CL;
    {
        int e = tid * 2;   // CL*32 = 512 floats
        int row = e >> 5, cc = e & 31;
        *(float2*)&BCs[row][cc] =
            *(const float2*)(dbl + ((size_t)(bb * L_ + l0 + row) * 96 + 64 + cc));
    }
    float Av[NS], S[NS];
#pragma unroll
    for (int n = 0; n < NS; ++n) { Av[n] = -__expf(A_log[d * NS + n]); S[n] = 0.f; }
    bool structured = true;
#pragma unroll
    for (int n = 1; n < NS; ++n)
        structured = structured &&
            (fabsf(Av[n] - (n + 1) * Av[0]) <= 1e-4f * (n + 1) * fabsf(Av[0]));
    const float bd2 = 2.f * bdt[d];
    const float Dd = Dv[d];
    float cd = 0.f;
    __syncthreads();
    float* __restrict__ up = u + ((size_t)bb * L_ + l0) * DI + d;
    float* __restrict__ dp = dtm + ((size_t)bb * L_ + l0) * DI + d;
    float draw = dp[0], ul = up[0];
    if (structured) {
        const float Av0 = Av[0];
        for (int l = 0; l < CL; ++l) {
            float draw_n = 0.f, ul_n = 0.f;
            if (l + 1 < CL) { draw_n = dp[(size_t)(l + 1) * DI]; ul_n = up[(size_t)(l + 1) * DI]; }
            float del = softplus2(draw, bd2);
            cd += del;
            float du = del * ul;
            float pw[NS];
            pow_tree(__expf(del * Av0), pw);
            const float* Brow = &BCs[l][0];
            float pa[4] = {0.f, 0.f, 0.f, 0.f};
#pragma unroll
            for (int j = 0; j < 4; ++j)
#pragma unroll
                for (int k = 0; k < 4; ++k) {
                    int n = j * 4 + k;
                    S[n] = fmaf(pw[n], S[n], du * Brow[n]);
                    pa[j] = fmaf(S[n], Brow[16 + n], pa[j]);
                }
            float acc = (pa[0] + pa[1]) + (pa[2] + pa[3]);
            dp[(size_t)l * DI] = cd;
            up[(size_t)l * DI] = acc + ul * Dd;
            draw = draw_n; ul = ul_n;
        }
    } else {
        for (int l = 0; l < CL; ++l) {
            float draw_n = 0.f, ul_n = 0.f;
            if (l + 1 < CL) { draw_n = dp[(size_t)(l + 1) * DI]; ul_n = up[(size_t)(l + 1) * DI]; }
            float del = softplus2(draw, bd2);
            cd += del;
            float du = del * ul;
            const float* Brow = &BCs[l][0];
            float pa[4] = {0.f, 0.f, 0.f, 0.f};
#pragma unroll
            for (int j = 0; j < 4; ++j)
#pragma unroll
                for (int k = 0; k < 4; ++k) {
                    int n = j * 4 + k;
                    float dA = __expf(del * Av[n]);
                    S[n] = fmaf(dA, S[n], du * Brow[n]);
                    pa[j] = fmaf(S[n], Brow[16 + n], pa[j]);
                }
            float acc = (pa[0] + pa[1]) + (pa[2] + pa[3]);
            dp[(size_t)l * DI] = cd;
            up[(size_t)l * DI] = acc + ul * Dd;
            draw = draw_n; ul = ul_n;
        }
    }
    size_t pb = ((size_t)(bb * NCH + c) * NS) * DI + d;
    if (structured) {
        float pw[NS];
        pow_tree(__expf(cd * Av[0]), pw);
#pragma unroll
        for (int n = 0; n < NS; ++n) {
            Pbuf[pb + (size_t)n * DI] = pw[n];
            Sbuf[pb + (size_t)n * DI] = S[n];
        }
    } else {
#pragma unroll
        for (int n = 0; n < NS; ++n) {
            Pbuf[pb + (size_t)n * DI] = __expf(cd * Av[n]);
            Sbuf[pb + (size_t)n * DI] = S[n];
        }
    }
}

// Pass B: one thread per (b,n,d); sequential over chunks. Pbuf[c] <- h_start[c].
__global__ void scan_combine(float* __restrict__ Pbuf, const float* __restrict__ Sbuf) {
    int g = blockIdx.x * blockDim.x + threadIdx.x;   // B_*NS*DI threads
    int d = g % DI;
    int rest = g / DI;
    int n = rest % NS, bb = rest / NS;
    float h = 0.f;
    for (int c = 0; c < NCH; ++c) {
        size_t o = ((size_t)(bb * NCH + c) * NS + n) * DI + d;
        float P = Pbuf[o], S = Sbuf[o];
        Pbuf[o] = h;
        h = P * h + S;
    }
}

// Pass C (correction, no recurrence): y[l] += sum_n C[l,n]*q^(n+1)*hs[n],
// q = exp(Av0*cd_l). Pipelined cd/y loads. Chunk 0 skipped.
__global__ void scan_apply(float* __restrict__ y, const float* __restrict__ cdm,
                           const float* __restrict__ dbl,
                           const float* __restrict__ A_log,
                           const float* __restrict__ Hbuf) {
    __shared__ float Cs[CL][16];
    const int tid = threadIdx.x;
    const int d = blockIdx.x * 256 + tid;
    const int bb = blockIdx.y, c = blockIdx.z + 1;
    const int l0 = c * CL;
    {
        int row = tid >> 4, cc = tid & 15;   // CL*16 = 256 floats
        Cs[row][cc] = dbl[(size_t)(bb * L_ + l0 + row) * 96 + 80 + cc];
    }
    float Av[NS], chs[NS];
#pragma unroll
    for (int n = 0; n < NS; ++n) Av[n] = -__expf(A_log[d * NS + n]);
    bool structured = true;
#pragma unroll
    for (int n = 1; n < NS; ++n)
        structured = structured &&
            (fabsf(Av[n] - (n + 1) * Av[0]) <= 1e-4f * (n + 1) * fabsf(Av[0]));
    size_t pb = ((size_t)(bb * NCH + c) * NS) * DI + d;
#pragma unroll
    for (int n = 0; n < NS; ++n) chs[n] = Hbuf[pb + (size_t)n * DI];
    __syncthreads();
    const float* __restrict__ cp = cdm + ((size_t)bb * L_ + l0) * DI + d;
    float* __restrict__ yp = y + ((size_t)bb * L_ + l0) * DI + d;
    float cdv = cp[0], yv = yp[0];
    if (structured) {
        const float Av0 = Av[0];
        for (int l = 0; l < CL; ++l) {
            float cdn = 0.f, yn = 0.f;
            if (l + 1 < CL) { cdn = cp[(size_t)(l + 1) * DI]; yn = yp[(size_t)(l + 1) * DI]; }
            float pw[NS];
            pow_tree(__expf(cdv * Av0), pw);
            const float* Crow = &Cs[l][0];
            float pa[4] = {0.f, 0.f, 0.f, 0.f};
#pragma unroll
            for (int j = 0; j < 4; ++j)
#pragma unroll
                for (int k = 0; k < 4; ++k) {
                    int n = j * 4 + k;
                    pa[j] = fmaf(pw[n], Crow[n] * chs[n], pa[j]);
                }
            yp[(size_t)l * DI] = yv + (pa[0] + pa[1]) + (pa[2] + pa[3]);
            cdv = cdn; yv = yn;
        }
    } else {
        for (int l = 0; l < CL; ++l) {
            float cdn = 0.f, yn = 0.f;
            if (l + 1 < CL) { cdn = cp[(size_t)(l + 1) * DI]; yn = yp[(size_t)(l + 1) * DI]; }
            const float* Crow = &Cs[l][0];
            float pa[4] = {0.f, 0.f, 0.f, 0.f};
#pragma unroll
            for (int j = 0; j < 4; ++j)
#pragma unroll
                for (int k = 0; k < 4; ++k) {
                    int n = j * 4 + k;
                    pa[j] = fmaf(__expf(cdv * Av[n]), Crow[n] * chs[n], pa[j]);
                }
            yp[(size_t)l * DI] = yv + (pa[0] + pa[1]) + (pa[2] + pa[3]);
            cdv = cdn; yv = yn;
        }
    }
}

// g = (y_f + flip(y_b)) * silu(z); rmsnorm; emit bf16 for the final MFMA GEMM.
__global__ void combine_rms(const float* __restrict__ yf, const float* __restrict__ yb,
                            const float* __restrict__ z,
                            const float* __restrict__ nw,
                            short* __restrict__ g) {
    int row = blockIdx.x;
    int bb = row / L_, l = row % L_;
    int tid = threadIdx.x;
    size_t base = (size_t)row * DI;
    size_t baseb = ((size_t)bb * L_ + (L_ - 1 - l)) * DI;
    float gv[8];
    float ss = 0.f;
#pragma unroll
    for (int j = 0; j < 8; ++j) {
        int d = tid + j * 256;
        float yy = yf[base + d] + yb[baseb + d];
        float zz = z[base + d];
        float s = zz / (1.f + __expf(-zz));
        float gg = yy * s;
        gv[j] = gg;
        ss += gg * gg;
    }
#pragma unroll
    for (int off = 32; off > 0; off >>= 1) ss += __shfl_down(ss, off, 64);
    __shared__ float red[4];
    if ((tid & 63) == 0) red[tid >> 6] = ss;
    __syncthreads();
    float tot = red[0] + red[1] + red[2] + red[3];
    float rms = rsqrtf(tot / (float)DI + 1e-5f);
#pragma unroll
    for (int j = 0; j < 8; ++j) {
        int d = tid + j * 256;
        g[base + d] = f2b(gv[j] * rms * nw[d]);
    }
}

extern "C" void kernel_launch(void* const* d_in, const int* in_sizes, int n_in,
                              void* d_out, int out_size, void* d_ws, size_t ws_size,
                              hipStream_t stream) {
    const float* a      = (const float*)d_in[0];
    const float* b      = (const float*)d_in[1];
    const float* Wi     = (const float*)d_in[2];
    const float* conv_w = (const float*)d_in[3];
    const float* conv_b = (const float*)d_in[4];
    const float* Wx     = (const float*)d_in[5];
    const float* Wdt    = (const float*)d_in[6];
    const float* bdt    = (const float*)d_in[7];
    const float* A_log  = (const float*)d_in[8];
    const float* Dvec   = (const float*)d_in[9];
    const float* conv_w_b = (const float*)d_in[10];
    const float* conv_b_b = (const float*)d_in[11];
    const float* Wx_b   = (const float*)d_in[12];
    const float* Wdt_b  = (const float*)d_in[13];
    const float* bdt_b  = (const float*)d_in[14];
    const float* A_log_b = (const float*)d_in[15];
    const float* Dvec_b = (const float*)d_in[16];
    const float* Wo     = (const float*)d_in[17];
    const float* nw     = (const float*)d_in[18];
    float* out = (float*)d_out;

    const int M = B_ * L_;              // 2048
    const size_t BLD = (size_t)M * DI;  // 4194304
    const size_t NDBL = (size_t)M * 96; // 196608
    const size_t PSsz = (size_t)NCH * B_ * NS * DI;   // 4.19M floats
    float* f = (float*)d_ws;
    float* B1   = f;                    // x_f -> cd_f | x_b -> cd_b -> z
    float* B2   = B1 + BLD;             // u_f -> y_f (final)
    float* B3   = B2 + BLD;             // u_b -> y_b (final)
    float* dblf = B3 + BLD;
    float* dblb = dblf + NDBL;
    float* Pbuf = dblb + NDBL;          // aliases split-K 'part' (lifetimes disjoint)
    float* part = Pbuf;
    float* Sbuf = Pbuf + PSsz;
    short* abf   = (short*)(Sbuf + PSsz);
    short* bbf   = abf + (size_t)M * DM;             // also gbf later
    short* Wibf  = bbf + (size_t)M * DM;
    short* cbf   = Wibf + (size_t)2 * DI * DM;
    short* Wxbf  = cbf + BLD;
    short* Wxbbf = Wxbf + (size_t)96 * DI;
    short* Wdtbf = Wxbbf + (size_t)96 * DI;
    short* Wdtbbf= Wdtbf + (size_t)DI * RR;
    short* dtbf  = Wdtbbf + (size_t)DI * RR;
    short* Wobf  = dtbf + (size_t)M * RR;
    short* gbf   = bbf;

    dim3 blk(256);
    const int totBLD = M * DI;
    dim3 chunkGrid(DI / 256, B_, NCH);
    dim3 applyGrid(DI / 256, B_, NCH - 1);
    const int nWeights = 2 * 96 * DI + 2 * DI * RR + DM * DI;

    // ---- casts ----
    cvt_bf16<<<dim3(M * DM / 256), blk, 0, stream>>>(a, abf, M, DM, L_, 0);
    cvt_bf16<<<dim3(M * DM / 256), blk, 0, stream>>>(b, bbf, M, DM, L_, 1);
    cvt_bf16<<<dim3(2 * DI * DM / 256), blk, 0, stream>>>(Wi, Wibf, 2 * DI, DM, L_, 0);
    cvt_weights<<<dim3((nWeights + 255) / 256), blk, 0, stream>>>(
        Wx, Wx_b, Wdt, Wdt_b, Wo, Wxbf, Wxbbf, Wdtbf, Wdtbbf, Wobf);

    // ---- forward branch ----
    gemm_mfma<128><<<dim3(DI / 64, M / 128), blk, 0, stream>>>(abf, DM, Wibf, DM, 0, B1, DI, DM);
    conv_silu_dual<<<dim3(totBLD / 256), blk, 0, stream>>>(B1, conv_w, conv_b, B2, cbf, totBLD);
    gemm_mfma_dbl<<<dim3(1, M / 128, NSPLIT), blk, 0, stream>>>(cbf, DI, Wxbf, DI, part, DI / NSPLIT);
    reduce_dbl<<<dim3((int)(NDBL / 256)), blk, 0, stream>>>(part, dblf, dtbf);
    gemm_mfma<64><<<dim3(DI / 64, M / 64), blk, 0, stream>>>(dtbf, RR, Wdtbf, RR, 0, B1, DI, RR);
    scan_chunk<<<chunkGrid, blk, 0, stream>>>(B2, B1, bdt, dblf, A_log, Dvec, Pbuf, Sbuf);
    scan_combine<<<dim3(B_ * NS * DI / 256), blk, 0, stream>>>(Pbuf, Sbuf);
    scan_apply<<<applyGrid, blk, 0, stream>>>(B2, B1, dblf, A_log, Pbuf);

    // ---- backward branch ----
    gemm_mfma<128><<<dim3(DI / 64, M / 128), blk, 0, stream>>>(bbf, DM, Wibf, DM, 0, B1, DI, DM);
    conv_silu_dual<<<dim3(totBLD / 256), blk, 0, stream>>>(B1, conv_w_b, conv_b_b, B3, cbf, totBLD);
    gemm_mfma_dbl<<<dim3(1, M / 128, NSPLIT), blk, 0, stream>>>(cbf, DI, Wxbbf, DI, part, DI / NSPLIT);
    reduce_dbl<<<dim3((int)(NDBL / 256)), blk, 0, stream>>>(part, dblb, dtbf);
    gemm_mfma<64><<<dim3(DI / 64, M / 64), blk, 0, stream>>>(dtbf, RR, Wdtbbf, RR, 0, B1, DI, RR);
    scan_chunk<<<chunkGrid, blk, 0, stream>>>(B3, B1, bdt_b, dblb, A_log_b, Dvec_b, Pbuf, Sbuf);
    scan_combine<<<dim3(B_ * NS * DI / 256), blk, 0, stream>>>(Pbuf, Sbuf);
    scan_apply<<<applyGrid, blk, 0, stream>>>(B3, B1, dblb, A_log_b, Pbuf);

    // ---- combine ----
    // z = a @ Wi[DI:2*DI].T -> B1 (cd_b dead)
    gemm_mfma<128><<<dim3(DI / 64, M / 128), blk, 0, stream>>>(abf, DM, Wibf, DM, DI, B1, DI, DM);
    combine_rms<<<dim3(M), blk, 0, stream>>>(B2, B3, B1, nw, gbf);
    gemm_mfma<64><<<dim3(DM / 64, M / 64), blk, 0, stream>>>(gbf, DI, Wobf, DI, 0, out, DM, DI);
}